// Round 5
// baseline (424.583 us; speedup 1.0000x reference)
//
#include <hip/hip_runtime.h>

#define HW 3136
#define NPOS 12845056   // 16*256*3136

__device__ __forceinline__ unsigned fkey(float f) {
  unsigned u = __float_as_uint(f);
  return (u & 0x80000000u) ? ~u : (u | 0x80000000u);
}
__device__ __forceinline__ float funkey(unsigned u) {
  return __uint_as_float((u & 0x80000000u) ? (u & 0x7FFFFFFFu) : ~u);
}
__device__ __forceinline__ float spikef(float x) {
  return fminf(fmaxf(rintf(x), 0.0f), 4.0f);
}
__device__ __forceinline__ float rdlane(float v, int src) {
  return __int_as_float(__builtin_amdgcn_readlane(__float_as_int(v), src));
}

// ---------------- Kernel 1: transposes + audio pre-projection + init ----------------
// w1t: [k 256][j 128]  (k-major; GEMM1 loads row k as coalesced per-lane float2)
// w2t: [k 128][j2 64]  (k-major; GEMM2 loads row k as coalesced per-lane float)
__global__ __launch_bounds__(256) void prep_kernel(
    const float* __restrict__ audio, const float* __restrict__ w1,
    const float* __restrict__ b1, const float* __restrict__ w2,
    float* __restrict__ a_pre, float* __restrict__ w1t,
    float* __restrict__ w2t, float* __restrict__ pool,
    unsigned* __restrict__ mm)
{
  __shared__ float au[256];
  const int bx = blockIdx.x, t = threadIdx.x;
  if (bx < 128) {                       // w1 visual half -> w1t[k][j]
    int idx = bx * 256 + t;             // 32768
    int c = idx >> 7, j = idx & 127;
    w1t[idx] = w1[j * 512 + c];
  } else if (bx < 160) {                // w2 -> w2t[k][j2]
    int idx = (bx - 128) * 256 + t;     // 8192
    int k = idx >> 6, j2 = idx & 63;
    w2t[idx] = w2[j2 * 128 + k];
  } else if (bx < 176) {                // a_pre[b][j] = b1[j] + w1[j][256:512].audio[b]
    int b = bx - 160;
    au[t] = audio[b * 256 + t];
    __syncthreads();
    int w = t >> 6, l = t & 63;
    float a0 = au[l], a1 = au[l + 64], a2 = au[l + 128], a3 = au[l + 192];
    for (int jj = 0; jj < 32; ++jj) {
      int j = w * 32 + jj;
      const float* row = w1 + j * 512 + 256;
      float s = row[l] * a0 + row[l + 64] * a1 + row[l + 128] * a2 + row[l + 192] * a3;
      #pragma unroll
      for (int off = 32; off; off >>= 1) s += __shfl_xor(s, off);
      if (l == 0) a_pre[b * 128 + j] = s + b1[j];
    }
  } else {
    for (int i = t; i < 4096; i += 256) pool[i] = 0.0f;
    if (t == 0) { mm[0] = 0xFFFFFFFFu; mm[1] = 0u; }
  }
}

// ---------------- Kernel 2: fused MLP + mi + pooling ----------------
// Round-11: latency-IMMUNE structure. Lane = j-pair (full j=128 in one wave),
// wave owns 8 positions. The fm tile (256k x 8pos = 8KB) is loaded ONCE into
// 32 VGPRs/lane up-front (one amortized latency hit); GEMM1/GEMM2 broadcast
// fm/h1 via v_readlane with compile-time lane indices (fully unrolled ->
// static reg indexing). Only in-loop memory stream: per-lane coalesced weight
// loads (vmcnt, L2-hot, straight-line scheduled). Pooling reuses the in-reg
// fm tile. ZERO LDS, ZERO barriers. Lessons enforced: no s_load in hot loop
// (SMEM is out-of-order -> lgkmcnt(0) drain kills prefetch, rounds 1-4).
__global__ __launch_bounds__(256, 4) void mlp_kernel(
    const float* __restrict__ fm, const float* __restrict__ w1t,
    const float* __restrict__ w2t, const float* __restrict__ b2,
    const float* __restrict__ w3, const float* __restrict__ b3,
    const float* __restrict__ g1, const float* __restrict__ be1,
    const float* __restrict__ g2, const float* __restrict__ be2,
    const float* __restrict__ a_pre, float* __restrict__ mi_out,
    float* __restrict__ pool, unsigned* __restrict__ mm)
{
  const int b  = blockIdx.y;
  const int t  = threadIdx.x;
  const int l  = t & 63;
  const int wv = __builtin_amdgcn_readfirstlane(t >> 6);  // 0..3, uniform
  const int pos0 = blockIdx.x * 32 + wv * 8;              // wave pos base
  const int j0 = 2 * l;                                   // lane j-pair

  // ---- fm tile -> 32 VGPRs: xr[r], lane l holds fm[r*8 + (l>>3)][l&7] ----
  const float* fmb = fm + (size_t)b * 256 * HW + pos0;
  const int kr = l >> 3, pp = l & 7;
  float xr[32];
  #pragma unroll
  for (int r = 0; r < 32; ++r)
    xr[r] = fmb[(size_t)(r * 8 + kr) * HW + pp];

  // ---- GEMM1: acc[p][j-pair] = sum_k fm[k][p] * w1t[k][j0..j0+1] ----
  float acc0[8], acc1[8];
  #pragma unroll
  for (int p = 0; p < 8; ++p) { acc0[p] = 0.f; acc1[p] = 0.f; }
  {
    const float* w1p = w1t + j0;                          // per-lane, coalesced
    #pragma unroll
    for (int k = 0; k < 256; ++k) {
      float2 w = *(const float2*)(w1p + (size_t)k * 128);
      const int r = k >> 3, g = (k & 7) << 3;             // compile-time
      #pragma unroll
      for (int p = 0; p < 8; ++p) {
        float x = rdlane(xr[r], g + p);
        acc0[p] = fmaf(x, w.x, acc0[p]);
        acc1[p] = fmaf(x, w.y, acc1[p]);
      }
    }
  }
  {   // bias + audio pre-projection (per j)
    float2 ap = *(const float2*)(a_pre + b * 128 + j0);
    #pragma unroll
    for (int p = 0; p < 8; ++p) { acc0[p] += ap.x; acc1[p] += ap.y; }
  }

  // ---- LN1 over j=128 (in-lane pair + 64-lane shfl tree), wave-local ----
  float mu_[8];
  #pragma unroll
  for (int p = 0; p < 8; ++p) {
    float s = acc0[p] + acc1[p];
    #pragma unroll
    for (int off = 32; off; off >>= 1) s += __shfl_xor(s, off);
    mu_[p] = s * (1.0f/128.0f);
  }
  float h1a[8], h1b[8];
  {
    float2 gv = *(const float2*)(g1 + j0);
    float2 bv = *(const float2*)(be1 + j0);
    #pragma unroll
    for (int p = 0; p < 8; ++p) {
      float d0 = acc0[p] - mu_[p], d1 = acc1[p] - mu_[p];
      float s2 = d0 * d0 + d1 * d1;
      #pragma unroll
      for (int off = 32; off; off >>= 1) s2 += __shfl_xor(s2, off);
      float inv = 1.0f / sqrtf(s2 * (1.0f/128.0f) + 1e-5f);
      h1a[p] = spikef(d0 * inv * gv.x + bv.x);
      h1b[p] = spikef(d1 * inv * gv.y + bv.y);
    }
  }

  // ---- GEMM2: a2[p] per j2=l; broadcast h1 via v_readlane (static idx) ----
  float a2[8];
  #pragma unroll
  for (int p = 0; p < 8; ++p) a2[p] = 0.f;
  {
    const float* w2p = w2t + l;                           // per-lane, coalesced
    #pragma unroll
    for (int m = 0; m < 64; ++m) {      // j = 2m (a), 2m+1 (b); src lane = m
      float wA = w2p[(2 * m) * 64];
      float wB = w2p[(2 * m + 1) * 64];
      #pragma unroll
      for (int p = 0; p < 8; ++p) {
        float xA = rdlane(h1a[p], m);
        float xB = rdlane(h1b[p], m);
        a2[p] = fmaf(xB, wB, fmaf(xA, wA, a2[p]));
      }
    }
  }

  // ---- LN2 over j2=64 (shfl tree) + spike + mi ----
  const float b2l = b2[l];
  #pragma unroll
  for (int p = 0; p < 8; ++p) a2[p] += b2l;
  float miv[8];
  {
    const float g2l = g2[l], be2l = be2[l], w3l = w3[l];
    const float b3v = b3[0];
    #pragma unroll
    for (int p = 0; p < 8; ++p) {
      float s = a2[p];
      #pragma unroll
      for (int off = 32; off; off >>= 1) s += __shfl_xor(s, off);
      float mu2 = s * (1.0f/64.0f);
      float d = a2[p] - mu2;
      float s2 = d * d;
      #pragma unroll
      for (int off = 32; off; off >>= 1) s2 += __shfl_xor(s2, off);
      float inv2 = 1.0f / sqrtf(s2 * (1.0f/64.0f) + 1e-5f);
      float sp = spikef(d * inv2 * g2l + be2l) * w3l;
      #pragma unroll
      for (int off = 32; off; off >>= 1) sp += __shfl_xor(sp, off);
      miv[p] = sp + b3v;                                  // uniform across lanes
    }
  }

  // ---- m_l = miv[l&7] (static select); store mi; global min/max ----
  float m_l = miv[0];
  #pragma unroll
  for (int p = 1; p < 8; ++p) m_l = (pp == p) ? miv[p] : m_l;
  if (l < 8) mi_out[b * HW + pos0 + l] = m_l;

  {
    float mn = miv[0], mx = miv[0];
    #pragma unroll
    for (int p = 1; p < 8; ++p) { mn = fminf(mn, miv[p]); mx = fmaxf(mx, miv[p]); }
    if (l == 0) {
      unsigned kmn = fkey(mn), kmx = fkey(mx);
      volatile unsigned* vmm = (volatile unsigned*)mm;
      if (kmn < vmm[0]) atomicMin(&mm[0], kmn);
      if (kmx > vmm[1]) atomicMax(&mm[1], kmx);
    }
  }

  // ---- pooling from the in-register fm tile ----
  // lane l holds fm[r*8+kr][pp]; multiply by mi[pp], sum over pp (8-lane
  // groups via shfl_xor 1/2/4), atomicAdd from lanes with pp==0.
  #pragma unroll
  for (int r = 0; r < 32; ++r) {
    float v = xr[r] * m_l;
    v += __shfl_xor(v, 1);
    v += __shfl_xor(v, 2);
    v += __shfl_xor(v, 4);
    if (pp == 0) atomicAdd(&pool[b * 256 + r * 8 + kr], v);
  }
}

// ---------------- Kernel 3: projection + LN + spike -> channel scale ----------------
__global__ __launch_bounds__(256) void scale_kernel(
    const float* __restrict__ pool, const float* __restrict__ pw,
    const float* __restrict__ pb, const float* __restrict__ pg,
    const float* __restrict__ pbeta, float* __restrict__ scale,
    const unsigned* __restrict__ mm, float* __restrict__ gpar)
{
  __shared__ float pl[256];
  __shared__ float xsh[256];
  __shared__ float rs[4], rs2[4];
  int b = blockIdx.x, t = threadIdx.x;
  pl[t] = pool[b*256 + t];
  __syncthreads();
  int w = t >> 6, l = t & 63;
  float p0 = pl[l], p1 = pl[l+64], p2 = pl[l+128], p3 = pl[l+192];
  for (int jj = 0; jj < 64; ++jj) {
    int j = w*64 + jj;
    const float* row = pw + j*256;
    float s = row[l]*p0 + row[l+64]*p1 + row[l+128]*p2 + row[l+192]*p3;
    #pragma unroll
    for (int off = 32; off; off >>= 1) s += __shfl_xor(s, off);
    if (l == 0) xsh[j] = s;
  }
  __syncthreads();
  float x = xsh[t] + pb[t];
  float s = x;
  #pragma unroll
  for (int off = 32; off; off >>= 1) s += __shfl_xor(s, off);
  if (l == 0) rs[w] = s;
  __syncthreads();
  float mu = (rs[0]+rs[1]+rs[2]+rs[3]) * (1.0f/256.0f);
  float d = x - mu;
  float s2 = d*d;
  #pragma unroll
  for (int off = 32; off; off >>= 1) s2 += __shfl_xor(s2, off);
  if (l == 0) rs2[w] = s2;
  __syncthreads();
  float var = (rs2[0]+rs2[1]+rs2[2]+rs2[3]) * (1.0f/256.0f);
  float v = d / sqrtf(var + 1e-5f) * pg[t] + pbeta[t];
  scale[b*256 + t] = spikef(v);
  if (b == 0 && t == 0) {
    float mn = funkey(mm[0]), mx = funkey(mm[1]);
    gpar[0] = mn;
    gpar[1] = mx - mn + 1e-6f;
  }
}

// ---------------- Kernel 4: fusion map + normalized mi map ----------------
__global__ __launch_bounds__(256) void fuse_kernel(
    const float4* __restrict__ fm4, const float* __restrict__ scale,
    const float4* __restrict__ mi4, const float* __restrict__ gpar,
    float4* __restrict__ out4, float4* __restrict__ mi4out)
{
  const int c = blockIdx.x, b = blockIdx.y, t = threadIdx.x;
  if (c < 256) {
    float s = scale[b * 256 + c];
    size_t base = ((size_t)b * 256 + c) * 784;
    #pragma unroll
    for (int i = 0; i < 3; ++i) {
      int idx = t + i * 256;
      float4 v = fm4[base + idx];
      out4[base + idx] = make_float4(v.x*s, v.y*s, v.z*s, v.w*s);
    }
    int idx = t + 768;
    if (idx < 784) {
      float4 v = fm4[base + idx];
      out4[base + idx] = make_float4(v.x*s, v.y*s, v.z*s, v.w*s);
    }
  } else {
    float gmin = gpar[0], den = gpar[1];
    size_t base = (size_t)b * 784;
    #pragma unroll
    for (int i = 0; i < 3; ++i) {
      int idx = t + i * 256;
      float4 v = mi4[base + idx];
      mi4out[base + idx] = make_float4((v.x-gmin)/den, (v.y-gmin)/den,
                                       (v.z-gmin)/den, (v.w-gmin)/den);
    }
    int idx = t + 768;
    if (idx < 784) {
      float4 v = mi4[base + idx];
      mi4out[base + idx] = make_float4((v.x-gmin)/den, (v.y-gmin)/den,
                                       (v.z-gmin)/den, (v.w-gmin)/den);
    }
  }
}

extern "C" void kernel_launch(void* const* d_in, const int* in_sizes, int n_in,
                              void* d_out, int out_size, void* d_ws, size_t ws_size,
                              hipStream_t stream)
{
  const float* fm    = (const float*)d_in[0];
  const float* audio = (const float*)d_in[1];
  const float* w1    = (const float*)d_in[2];
  const float* b1    = (const float*)d_in[3];
  const float* g1    = (const float*)d_in[4];
  const float* be1   = (const float*)d_in[5];
  const float* w2    = (const float*)d_in[6];
  const float* b2    = (const float*)d_in[7];
  const float* g2    = (const float*)d_in[8];
  const float* be2   = (const float*)d_in[9];
  const float* w3    = (const float*)d_in[10];
  const float* b3    = (const float*)d_in[11];
  const float* pw    = (const float*)d_in[12];
  const float* pb    = (const float*)d_in[13];
  const float* pg    = (const float*)d_in[14];
  const float* pbeta = (const float*)d_in[15];

  float* ws    = (float*)d_ws;
  float* a_pre = ws;               // 2048 floats
  float* pool  = ws + 2048;        // 4096
  float* scale = ws + 6144;        // 4096
  float* mi    = ws + 10240;       // 50176 (16B aligned)
  float* w1t   = ws + 60416;       // 32768  [k][j]
  float* w2t   = ws + 93184;       // 8192   [k][j2]
  unsigned* mm = (unsigned*)(ws + 101376);  // 2 keys
  float* gpar  = ws + 101378;      // gmin, denom

  float* out    = (float*)d_out;
  float* mi4out = out + NPOS;

  prep_kernel<<<177, 256, 0, stream>>>(audio, w1, b1, w2, a_pre, w1t, w2t,
                                       pool, mm);
  mlp_kernel<<<dim3(98, 16), 256, 0, stream>>>(fm, w1t, w2t, b2, w3, b3,
                                               g1, be1, g2, be2,
                                               a_pre, mi, pool, mm);
  scale_kernel<<<16, 256, 0, stream>>>(pool, pw, pb, pg, pbeta, scale, mm, gpar);
  fuse_kernel<<<dim3(257, 16), 256, 0, stream>>>((const float4*)fm, scale,
                                                 (const float4*)mi, gpar,
                                                 (float4*)out, (float4*)mi4out);
}

// Round 7
// 327.467 us; speedup vs baseline: 1.2966x; 1.2966x over previous
//
#include <hip/hip_runtime.h>

#define HW 3136
#define NPOS 12845056   // 16*256*3136

__device__ __forceinline__ unsigned fkey(float f) {
  unsigned u = __float_as_uint(f);
  return (u & 0x80000000u) ? ~u : (u | 0x80000000u);
}
__device__ __forceinline__ float funkey(unsigned u) {
  return __uint_as_float((u & 0x80000000u) ? (u & 0x7FFFFFFFu) : ~u);
}
__device__ __forceinline__ float spikef(float x) {
  return fminf(fmaxf(rintf(x), 0.0f), 4.0f);
}

// ---------------- Kernel 1: transposes + audio pre-projection + init ----------------
// w1t: [k 256][j 128]  (k-major; staged to LDS in 32KB chunks)
// w2t: [k 128][j2 64]  (k-major; GEMM2 per-lane coalesced dword stream)
__global__ __launch_bounds__(256) void prep_kernel(
    const float* __restrict__ audio, const float* __restrict__ w1,
    const float* __restrict__ b1, const float* __restrict__ w2,
    float* __restrict__ a_pre, float* __restrict__ w1t,
    float* __restrict__ w2t, float* __restrict__ pool,
    unsigned* __restrict__ mm)
{
  __shared__ float au[256];
  const int bx = blockIdx.x, t = threadIdx.x;
  if (bx < 128) {                       // w1 visual half -> w1t[k][j]
    int idx = bx * 256 + t;             // 32768
    int c = idx >> 7, j = idx & 127;
    w1t[idx] = w1[j * 512 + c];
  } else if (bx < 160) {                // w2 -> w2t[k][j2]
    int idx = (bx - 128) * 256 + t;     // 8192
    int k = idx >> 6, j2 = idx & 63;
    w2t[idx] = w2[j2 * 128 + k];
  } else if (bx < 176) {                // a_pre[b][j] = b1[j] + w1[j][256:512].audio[b]
    int b = bx - 160;
    au[t] = audio[b * 256 + t];
    __syncthreads();
    int w = t >> 6, l = t & 63;
    float a0 = au[l], a1 = au[l + 64], a2 = au[l + 128], a3 = au[l + 192];
    for (int jj = 0; jj < 32; ++jj) {
      int j = w * 32 + jj;
      const float* row = w1 + j * 512 + 256;
      float s = row[l] * a0 + row[l + 64] * a1 + row[l + 128] * a2 + row[l + 192] * a3;
      #pragma unroll
      for (int off = 32; off; off >>= 1) s += __shfl_xor(s, off);
      if (l == 0) a_pre[b * 128 + j] = s + b1[j];
    }
  } else {
    for (int i = t; i < 4096; i += 256) pool[i] = 0.0f;
    if (t == 0) { mm[0] = 0xFFFFFFFFu; mm[1] = 0u; }
  }
}

// ---------------- Kernel 2: fused MLP + mi + pooling ----------------
// Round-13 = round-12 resubmit (container failed) with the global_load_lds
// staging hardened: LDS dst is now SYNTACTICALLY wave-uniform (HW adds
// lane*16B); per-lane offset lives only on the global src (the proven
// round-0 pattern, per m104/m108 contract). Theory unchanged: exactly 1
// VMEM per k (coalesced fm dword); weights from LDS UNIFORM ds_read_b128
// (same-address broadcast, separate DS pipe) -> takes the weight stream off
// the saturated VMEM path that pinned VALUBusy at 24-37% for 5 rounds.
__global__ __launch_bounds__(256, 3) void mlp_kernel(
    const float* __restrict__ fm, const float* __restrict__ w1t,
    const float* __restrict__ w2t, const float* __restrict__ b2,
    const float* __restrict__ w3, const float* __restrict__ b3,
    const float* __restrict__ g1, const float* __restrict__ be1,
    const float* __restrict__ g2, const float* __restrict__ be2,
    const float* __restrict__ a_pre, float* __restrict__ mi_out,
    float* __restrict__ pool, unsigned* __restrict__ mm)
{
  __shared__ __align__(16) float wbuf[8192];  // 32 KB: w1 chunk [64][128]; later h1f[128][64]
  __shared__ float red[2][4][64];             // 2 KB LN partials
  __shared__ float miL[64];

  const int b  = blockIdx.y;
  const int s0 = blockIdx.x * 64;
  const int t  = threadIdx.x;
  const int l  = t & 63;                                   // GEMM1: lane = pos
  const int wv = __builtin_amdgcn_readfirstlane(t >> 6);   // 0..3, uniform

  const float* fmblk = fm + (size_t)b * 256 * HW + s0;
  const float* fp = fmblk + l;

  // ---- GEMM1: acc[j] = sum_k fm[k][pos] * w1t[k][wv*32+j], K=256 ----
  float acc[32];
  #pragma unroll
  for (int j = 0; j < 32; ++j) acc[j] = 0.f;

  #pragma unroll 1
  for (int ch = 0; ch < 4; ++ch) {
    if (ch) __syncthreads();              // protect wbuf before restage
    {
      // wave-uniform LDS dst; per-lane global src (lane l -> dst + l*16B)
      const float* src = w1t + ch * 8192 + wv * 256 + l * 4;
      float* dst = wbuf + wv * 256;
      #pragma unroll
      for (int i = 0; i < 8; ++i)
        __builtin_amdgcn_global_load_lds(
            (const __attribute__((address_space(1))) void*)(src + i * 1024),
            (__attribute__((address_space(3))) void*)(dst + i * 1024), 16, 0, 0);
    }
    __syncthreads();                      // chunk resident
    const float* wrow = wbuf + wv * 32;   // uniform
    #pragma unroll 2
    for (int k = 0; k < 64; ++k) {
      float x = fp[(size_t)(ch * 64 + k) * HW];            // 1 VMEM / k
      const float* wk = wrow + k * 128;
      float4 q0 = *(const float4*)(wk);                    // uniform ds_read_b128
      float4 q1 = *(const float4*)(wk + 4);
      float4 q2 = *(const float4*)(wk + 8);
      float4 q3 = *(const float4*)(wk + 12);
      float4 q4 = *(const float4*)(wk + 16);
      float4 q5 = *(const float4*)(wk + 20);
      float4 q6 = *(const float4*)(wk + 24);
      float4 q7 = *(const float4*)(wk + 28);
      acc[ 0] = fmaf(x, q0.x, acc[ 0]); acc[ 1] = fmaf(x, q0.y, acc[ 1]);
      acc[ 2] = fmaf(x, q0.z, acc[ 2]); acc[ 3] = fmaf(x, q0.w, acc[ 3]);
      acc[ 4] = fmaf(x, q1.x, acc[ 4]); acc[ 5] = fmaf(x, q1.y, acc[ 5]);
      acc[ 6] = fmaf(x, q1.z, acc[ 6]); acc[ 7] = fmaf(x, q1.w, acc[ 7]);
      acc[ 8] = fmaf(x, q2.x, acc[ 8]); acc[ 9] = fmaf(x, q2.y, acc[ 9]);
      acc[10] = fmaf(x, q2.z, acc[10]); acc[11] = fmaf(x, q2.w, acc[11]);
      acc[12] = fmaf(x, q3.x, acc[12]); acc[13] = fmaf(x, q3.y, acc[13]);
      acc[14] = fmaf(x, q3.z, acc[14]); acc[15] = fmaf(x, q3.w, acc[15]);
      acc[16] = fmaf(x, q4.x, acc[16]); acc[17] = fmaf(x, q4.y, acc[17]);
      acc[18] = fmaf(x, q4.z, acc[18]); acc[19] = fmaf(x, q4.w, acc[19]);
      acc[20] = fmaf(x, q5.x, acc[20]); acc[21] = fmaf(x, q5.y, acc[21]);
      acc[22] = fmaf(x, q5.z, acc[22]); acc[23] = fmaf(x, q5.w, acc[23]);
      acc[24] = fmaf(x, q6.x, acc[24]); acc[25] = fmaf(x, q6.y, acc[25]);
      acc[26] = fmaf(x, q6.z, acc[26]); acc[27] = fmaf(x, q6.w, acc[27]);
      acc[28] = fmaf(x, q7.x, acc[28]); acc[29] = fmaf(x, q7.y, acc[29]);
      acc[30] = fmaf(x, q7.z, acc[30]); acc[31] = fmaf(x, q7.w, acc[31]);
    }
  }
  {   // bias + audio pre-projection (uniform per j)
    const float4* ap = (const float4*)(a_pre + b * 128 + wv * 32);
    #pragma unroll
    for (int q = 0; q < 8; ++q) {
      float4 a4 = ap[q];
      acc[4*q+0] += a4.x; acc[4*q+1] += a4.y;
      acc[4*q+2] += a4.z; acc[4*q+3] += a4.w;
    }
  }

  // ---- LN1 over j=128 (32 in-thread + 4-way cross-wave) ----
  float mu, inv;
  {
    float s = 0.f;
    #pragma unroll
    for (int j = 0; j < 32; ++j) s += acc[j];
    red[0][wv][l] = s;
    __syncthreads();
    mu = (red[0][0][l] + red[0][1][l] + red[0][2][l] + red[0][3][l]) * (1.0f/128.0f);
    float s2 = 0.f;
    #pragma unroll
    for (int j = 0; j < 32; ++j) { float d = acc[j] - mu; s2 = fmaf(d, d, s2); }
    red[1][wv][l] = s2;
    __syncthreads();
    float var = (red[1][0][l] + red[1][1][l] + red[1][2][l] + red[1][3][l]) * (1.0f/128.0f);
    inv = 1.0f / sqrtf(var + 1e-5f);
  }
  // (LN1 barriers also guarantee all waves finished reading wbuf chunk 3)

  // ---- spike -> h1f[j][pos] in wbuf (aliased) ----
  {
    const float* gp = g1  + wv * 32;
    const float* bp = be1 + wv * 32;
    #pragma unroll
    for (int j = 0; j < 32; ++j) {
      float h = spikef((acc[j] - mu) * inv * gp[j] + bp[j]);
      wbuf[(wv * 32 + j) * 64 + l] = h;       // 2-way bank, free
    }
  }
  __syncthreads();                             // h1f resident

  // ---- GEMM2 (remapped): lane = j2, wave = 16-pos slice ----
  // a2[p] = sum_k2 h1[k2][wv*16+p] * w2t[k2][l]
  float a2[16];
  #pragma unroll
  for (int p = 0; p < 16; ++p) a2[p] = 0.f;
  {
    const float* hrow = wbuf + wv * 16;        // uniform
    const float* w2p  = w2t + l;               // per-lane, coalesced
    #pragma unroll 2
    for (int k2 = 0; k2 < 128; ++k2) {
      float w = w2p[k2 * 64];                  // 1 VMEM / k2
      const float* hk = hrow + k2 * 64;
      float4 x0 = *(const float4*)(hk);        // uniform ds_read_b128
      float4 x1 = *(const float4*)(hk + 4);
      float4 x2 = *(const float4*)(hk + 8);
      float4 x3 = *(const float4*)(hk + 12);
      a2[ 0] = fmaf(x0.x, w, a2[ 0]); a2[ 1] = fmaf(x0.y, w, a2[ 1]);
      a2[ 2] = fmaf(x0.z, w, a2[ 2]); a2[ 3] = fmaf(x0.w, w, a2[ 3]);
      a2[ 4] = fmaf(x1.x, w, a2[ 4]); a2[ 5] = fmaf(x1.y, w, a2[ 5]);
      a2[ 6] = fmaf(x1.z, w, a2[ 6]); a2[ 7] = fmaf(x1.w, w, a2[ 7]);
      a2[ 8] = fmaf(x2.x, w, a2[ 8]); a2[ 9] = fmaf(x2.y, w, a2[ 9]);
      a2[10] = fmaf(x2.z, w, a2[10]); a2[11] = fmaf(x2.w, w, a2[11]);
      a2[12] = fmaf(x3.x, w, a2[12]); a2[13] = fmaf(x3.y, w, a2[13]);
      a2[14] = fmaf(x3.z, w, a2[14]); a2[15] = fmaf(x3.w, w, a2[15]);
    }
  }
  {
    const float b2l = b2[l];                   // per-lane (j2 = l)
    #pragma unroll
    for (int p = 0; p < 16; ++p) a2[p] += b2l;
  }

  // ---- LN2 over j2=64 (lane dim -> wave-local shfl trees) + spike + mi ----
  float miv[16];
  {
    const float g2l = g2[l], be2l = be2[l], w3l = w3[l];
    const float b3v = b3[0];
    #pragma unroll
    for (int p = 0; p < 16; ++p) {
      float s = a2[p];
      #pragma unroll
      for (int off = 32; off; off >>= 1) s += __shfl_xor(s, off);
      float mu2 = s * (1.0f/64.0f);
      float d = a2[p] - mu2;
      float s2 = d * d;
      #pragma unroll
      for (int off = 32; off; off >>= 1) s2 += __shfl_xor(s2, off);
      float inv2 = 1.0f / sqrtf(s2 * (1.0f/64.0f) + 1e-5f);
      float sp = spikef(d * inv2 * g2l + be2l) * w3l;
      #pragma unroll
      for (int off = 32; off; off >>= 1) sp += __shfl_xor(sp, off);
      miv[p] = sp + b3v;                       // uniform across lanes
    }
  }

  // ---- select lane's pos value, store mi + miL ----
  {
    float m = miv[0];
    #pragma unroll
    for (int p = 1; p < 16; ++p) m = (l == p) ? miv[p] : m;
    if (l < 16) {
      mi_out[b * HW + s0 + wv * 16 + l] = m;
      miL[wv * 16 + l] = m;
    }
  }
  __syncthreads();                             // miL resident

  // ---- global min/max (wave 0 over the block's 64 positions) ----
  if (wv == 0) {
    float v = miL[l];
    float mn = v, mx = v;
    #pragma unroll
    for (int off = 32; off; off >>= 1) {
      mn = fminf(mn, __shfl_xor(mn, off));
      mx = fmaxf(mx, __shfl_xor(mx, off));
    }
    if (l == 0) {
      unsigned kmn = fkey(mn), kmx = fkey(mx);
      volatile unsigned* vmm = (volatile unsigned*)mm;
      if (kmn < vmm[0]) atomicMin(&mm[0], kmn);
      if (kmx > vmm[1]) atomicMax(&mm[1], kmx);
    }
  }

  // ---- pooling: pool[b][c] += sum_pos mi[pos]*fm[b][c][pos], 64 c/wave ----
  {
    const float mval = miL[l];
    const float* fp2 = fmblk + l + (size_t)(wv << 6) * HW;
    #pragma unroll 4
    for (int ci = 0; ci < 64; ++ci) {
      float v = fp2[(size_t)ci * HW] * mval;
      #pragma unroll
      for (int off = 32; off; off >>= 1) v += __shfl_xor(v, off);
      if (l == 0) atomicAdd(&pool[b * 256 + (wv << 6) + ci], v);
    }
  }
}

// ---------------- Kernel 3: projection + LN + spike -> channel scale ----------------
__global__ __launch_bounds__(256) void scale_kernel(
    const float* __restrict__ pool, const float* __restrict__ pw,
    const float* __restrict__ pb, const float* __restrict__ pg,
    const float* __restrict__ pbeta, float* __restrict__ scale,
    const unsigned* __restrict__ mm, float* __restrict__ gpar)
{
  __shared__ float pl[256];
  __shared__ float xsh[256];
  __shared__ float rs[4], rs2[4];
  int b = blockIdx.x, t = threadIdx.x;
  pl[t] = pool[b*256 + t];
  __syncthreads();
  int w = t >> 6, l = t & 63;
  float p0 = pl[l], p1 = pl[l+64], p2 = pl[l+128], p3 = pl[l+192];
  for (int jj = 0; jj < 64; ++jj) {
    int j = w*64 + jj;
    const float* row = pw + j*256;
    float s = row[l]*p0 + row[l+64]*p1 + row[l+128]*p2 + row[l+192]*p3;
    #pragma unroll
    for (int off = 32; off; off >>= 1) s += __shfl_xor(s, off);
    if (l == 0) xsh[j] = s;
  }
  __syncthreads();
  float x = xsh[t] + pb[t];
  float s = x;
  #pragma unroll
  for (int off = 32; off; off >>= 1) s += __shfl_xor(s, off);
  if (l == 0) rs[w] = s;
  __syncthreads();
  float mu = (rs[0]+rs[1]+rs[2]+rs[3]) * (1.0f/256.0f);
  float d = x - mu;
  float s2 = d*d;
  #pragma unroll
  for (int off = 32; off; off >>= 1) s2 += __shfl_xor(s2, off);
  if (l == 0) rs2[w] = s2;
  __syncthreads();
  float var = (rs2[0]+rs2[1]+rs2[2]+rs2[3]) * (1.0f/256.0f);
  float v = d / sqrtf(var + 1e-5f) * pg[t] + pbeta[t];
  scale[b*256 + t] = spikef(v);
  if (b == 0 && t == 0) {
    float mn = funkey(mm[0]), mx = funkey(mm[1]);
    gpar[0] = mn;
    gpar[1] = mx - mn + 1e-6f;
  }
}

// ---------------- Kernel 4: fusion map + normalized mi map ----------------
__global__ __launch_bounds__(256) void fuse_kernel(
    const float4* __restrict__ fm4, const float* __restrict__ scale,
    const float4* __restrict__ mi4, const float* __restrict__ gpar,
    float4* __restrict__ out4, float4* __restrict__ mi4out)
{
  const int c = blockIdx.x, b = blockIdx.y, t = threadIdx.x;
  if (c < 256) {
    float s = scale[b * 256 + c];
    size_t base = ((size_t)b * 256 + c) * 784;
    #pragma unroll
    for (int i = 0; i < 3; ++i) {
      int idx = t + i * 256;
      float4 v = fm4[base + idx];
      out4[base + idx] = make_float4(v.x*s, v.y*s, v.z*s, v.w*s);
    }
    int idx = t + 768;
    if (idx < 784) {
      float4 v = fm4[base + idx];
      out4[base + idx] = make_float4(v.x*s, v.y*s, v.z*s, v.w*s);
    }
  } else {
    float gmin = gpar[0], den = gpar[1];
    size_t base = (size_t)b * 784;
    #pragma unroll
    for (int i = 0; i < 3; ++i) {
      int idx = t + i * 256;
      float4 v = mi4[base + idx];
      mi4out[base + idx] = make_float4((v.x-gmin)/den, (v.y-gmin)/den,
                                       (v.z-gmin)/den, (v.w-gmin)/den);
    }
    int idx = t + 768;
    if (idx < 784) {
      float4 v = mi4[base + idx];
      mi4out[base + idx] = make_float4((v.x-gmin)/den, (v.y-gmin)/den,
                                       (v.z-gmin)/den, (v.w-gmin)/den);
    }
  }
}

extern "C" void kernel_launch(void* const* d_in, const int* in_sizes, int n_in,
                              void* d_out, int out_size, void* d_ws, size_t ws_size,
                              hipStream_t stream)
{
  const float* fm    = (const float*)d_in[0];
  const float* audio = (const float*)d_in[1];
  const float* w1    = (const float*)d_in[2];
  const float* b1    = (const float*)d_in[3];
  const float* g1    = (const float*)d_in[4];
  const float* be1   = (const float*)d_in[5];
  const float* w2    = (const float*)d_in[6];
  const float* b2    = (const float*)d_in[7];
  const float* g2    = (const float*)d_in[8];
  const float* be2   = (const float*)d_in[9];
  const float* w3    = (const float*)d_in[10];
  const float* b3    = (const float*)d_in[11];
  const float* pw    = (const float*)d_in[12];
  const float* pb    = (const float*)d_in[13];
  const float* pg    = (const float*)d_in[14];
  const float* pbeta = (const float*)d_in[15];

  float* ws    = (float*)d_ws;
  float* a_pre = ws;               // 2048 floats
  float* pool  = ws + 2048;        // 4096
  float* scale = ws + 6144;        // 4096
  float* mi    = ws + 10240;       // 50176 (16B aligned)
  float* w1t   = ws + 60416;       // 32768  [k][j]
  float* w2t   = ws + 93184;       // 8192   [k][j2]
  unsigned* mm = (unsigned*)(ws + 101376);  // 2 keys
  float* gpar  = ws + 101378;      // gmin, denom

  float* out    = (float*)d_out;
  float* mi4out = out + NPOS;

  prep_kernel<<<177, 256, 0, stream>>>(audio, w1, b1, w2, a_pre, w1t, w2t,
                                       pool, mm);
  mlp_kernel<<<dim3(49, 16), 256, 0, stream>>>(fm, w1t, w2t, b2, w3, b3,
                                               g1, be1, g2, be2,
                                               a_pre, mi, pool, mm);
  scale_kernel<<<16, 256, 0, stream>>>(pool, pw, pb, pg, pbeta, scale, mm, gpar);
  fuse_kernel<<<dim3(257, 16), 256, 0, stream>>>((const float4*)fm, scale,
                                                 (const float4*)mi, gpar,
                                                 (float4*)out, (float4*)mi4out);
}